// Round 2
// baseline (660.700 us; speedup 1.0000x reference)
//
#include <hip/hip_runtime.h>

// fp16 vector types for MFMA fragments
typedef _Float16 hf2 __attribute__((ext_vector_type(2)));
typedef _Float16 hf4 __attribute__((ext_vector_type(4)));
typedef _Float16 hf8 __attribute__((ext_vector_type(8)));
typedef float    fx4 __attribute__((ext_vector_type(4)));

// async global->LDS, 16B per lane; LDS dest must be lane-linear (base + lane*16)
#define GLD16(gp, lp) __builtin_amdgcn_global_load_lds(                      \
    (const __attribute__((address_space(1))) void*)(gp),                     \
    (__attribute__((address_space(3))) void*)(lp), 16, 0, 0)

// ---------------- f32 -> f16 conversion ----------------
__global__ __launch_bounds__(256) void cvt_x_k(const float* __restrict__ s,
                                               _Float16* __restrict__ d) {
  size_t i = (size_t)blockIdx.x * 256 + threadIdx.x;  // grid 4096 -> 1,048,576 float4s
  float4 v = ((const float4*)s)[i];
  hf4 o = {(_Float16)v.x, (_Float16)v.y, (_Float16)v.z, (_Float16)v.w};
  *(hf4*)(d + 4 * i) = o;
}

__global__ __launch_bounds__(256) void cvt_w_k(const float* __restrict__ s0,
                                               const float* __restrict__ s1,
                                               const float* __restrict__ s2,
                                               const float* __restrict__ s3,
                                               _Float16* __restrict__ d) {
  const float* s = blockIdx.y == 0 ? s0 : blockIdx.y == 1 ? s1 : blockIdx.y == 2 ? s2 : s3;
  size_t i = (size_t)blockIdx.x * 256 + threadIdx.x;  // grid.x 1024 -> 262,144 float4s
  float4 v = ((const float4*)s)[i];
  hf4 o = {(_Float16)v.x, (_Float16)v.y, (_Float16)v.z, (_Float16)v.w};
  *(hf4*)(d + (size_t)blockIdx.y * 1048576 + 4 * i) = o;
}

// ---------------- 128x128 tile GEMM, C = A[M,1024] * B[N,1024]^T + bias ----------------
// mode 0: C f16, bias over n (Q,K).  mode 1: C f16, bias over m (Vt, operands swapped
// by caller so output comes out transposed).  mode 2: C f32, bias over n (out-proj).
// LDS chunk swizzle: 16B chunk ch of row r stored at physical chunk ch ^ ((r>>1)&3)
// (applied by pre-swizzling the global source; LDS dest stays lane-linear).
__device__ __forceinline__ void gemm_tile(
    const _Float16* __restrict__ A, const _Float16* __restrict__ B,
    const float* __restrict__ bias, _Float16* __restrict__ Ch,
    float* __restrict__ Cf, int m0, int n0, int ldc, int mode)
{
  __shared__ alignas(16) _Float16 Asm[2][128 * 32];
  __shared__ alignas(16) _Float16 Bsm[2][128 * 32];
  const int tid = (int)threadIdx.x;
  const int lane = tid & 63, wv = tid >> 6;
  const int col = lane & 15, g = lane >> 4;

  fx4 acc[2][8];
#pragma unroll
  for (int i = 0; i < 2; ++i)
#pragma unroll
    for (int j = 0; j < 8; ++j) acc[i][j] = fx4{0.f, 0.f, 0.f, 0.f};

  const int cp0 = tid, cp1 = tid + 256;
  const int row0 = cp0 >> 2, row1 = cp1 >> 2;
  const int ch0 = (cp0 & 3) ^ ((row0 >> 1) & 3);
  const int ch1 = (cp1 & 3) ^ ((row1 >> 1) & 3);
  const _Float16* a0 = A + (size_t)(m0 + row0) * 1024 + ch0 * 8;
  const _Float16* a1 = A + (size_t)(m0 + row1) * 1024 + ch1 * 8;
  const _Float16* b0 = B + (size_t)(n0 + row0) * 1024 + ch0 * 8;
  const _Float16* b1 = B + (size_t)(n0 + row1) * 1024 + ch1 * 8;

  int aoff[2], boff[8];
#pragma unroll
  for (int mi = 0; mi < 2; ++mi) {
    int row = wv * 32 + mi * 16 + col;
    aoff[mi] = (row * 4 + (g ^ ((row >> 1) & 3))) * 8;
  }
#pragma unroll
  for (int nj = 0; nj < 8; ++nj) {
    int row = nj * 16 + col;
    boff[nj] = (row * 4 + (g ^ ((row >> 1) & 3))) * 8;
  }

#define STAGE_T(bufi, kt) {                          \
    GLD16(a0 + (kt) * 32, &Asm[bufi][cp0 * 8]);      \
    GLD16(a1 + (kt) * 32, &Asm[bufi][cp1 * 8]);      \
    GLD16(b0 + (kt) * 32, &Bsm[bufi][cp0 * 8]);      \
    GLD16(b1 + (kt) * 32, &Bsm[bufi][cp1 * 8]); }

  STAGE_T(0, 0);
  int buf = 0;
  for (int kt = 0; kt < 32; ++kt) {
    __syncthreads();
    if (kt + 1 < 32) STAGE_T(buf ^ 1, kt + 1);
    hf8 af[2], bf[8];
#pragma unroll
    for (int mi = 0; mi < 2; ++mi) af[mi] = *(const hf8*)&Asm[buf][aoff[mi]];
#pragma unroll
    for (int nj = 0; nj < 8; ++nj) bf[nj] = *(const hf8*)&Bsm[buf][boff[nj]];
#pragma unroll
    for (int mi = 0; mi < 2; ++mi)
#pragma unroll
      for (int nj = 0; nj < 8; ++nj)
        acc[mi][nj] = __builtin_amdgcn_mfma_f32_16x16x32_f16(af[mi], bf[nj], acc[mi][nj], 0, 0, 0);
    buf ^= 1;
  }
#undef STAGE_T

  if (mode == 2) {
#pragma unroll
    for (int nj = 0; nj < 8; ++nj) {
      float bn = bias[n0 + nj * 16 + col];
#pragma unroll
      for (int mi = 0; mi < 2; ++mi)
#pragma unroll
        for (int r = 0; r < 4; ++r)
          Cf[(size_t)(m0 + wv * 32 + mi * 16 + 4 * g + r) * ldc + n0 + nj * 16 + col] =
              acc[mi][nj][r] + bn;
    }
  } else if (mode == 0) {
#pragma unroll
    for (int nj = 0; nj < 8; ++nj) {
      float bn = bias[n0 + nj * 16 + col];
#pragma unroll
      for (int mi = 0; mi < 2; ++mi)
#pragma unroll
        for (int r = 0; r < 4; ++r)
          Ch[(size_t)(m0 + wv * 32 + mi * 16 + 4 * g + r) * ldc + n0 + nj * 16 + col] =
              (_Float16)(acc[mi][nj][r] + bn);
    }
  } else {  // mode 1: bias over m
#pragma unroll
    for (int mi = 0; mi < 2; ++mi)
#pragma unroll
      for (int r = 0; r < 4; ++r) {
        float bm = bias[m0 + wv * 32 + mi * 16 + 4 * g + r];
#pragma unroll
        for (int nj = 0; nj < 8; ++nj)
          Ch[(size_t)(m0 + wv * 32 + mi * 16 + 4 * g + r) * ldc + n0 + nj * 16 + col] =
              (_Float16)(acc[mi][nj][r] + bm);
      }
  }
}

// QKV: blocks 0..255 -> Q, 256..511 -> K, 512..767 -> Vt (A=Wv, B=x -> transposed out)
__global__ __launch_bounds__(256, 3) void qkv_gemm_k(
    const _Float16* __restrict__ xh, const _Float16* __restrict__ Wqh,
    const _Float16* __restrict__ Wkh, const _Float16* __restrict__ Wvh,
    const float* __restrict__ bq, const float* __restrict__ bk,
    const float* __restrict__ bv, _Float16* __restrict__ Qh,
    _Float16* __restrict__ Kh, _Float16* __restrict__ Vt)
{
  int id = (int)blockIdx.x;
  if (id < 512) {
    int t = id & 255;
    const _Float16* Bp = (id < 256) ? Wqh : Wkh;
    const float*    bp = (id < 256) ? bq : bk;
    _Float16*       Cp = (id < 256) ? Qh : Kh;
    gemm_tile(xh, Bp, bp, Cp, nullptr, (t >> 3) * 128, (t & 7) * 128, 1024, 0);
  } else {
    int t = id - 512;  // M=1024 (e), N=4096 (b*s)
    gemm_tile(Wvh, xh, bv, Vt, nullptr, (t >> 5) * 128, (t & 31) * 128, 4096, 1);
  }
}

__global__ __launch_bounds__(256, 3) void out_gemm_k(
    const _Float16* __restrict__ Oh, const _Float16* __restrict__ Woh,
    const float* __restrict__ bo, float* __restrict__ outp)
{
  int id = (int)blockIdx.x;
  gemm_tile(Oh, Woh, bo, nullptr, outp, (id >> 3) * 128, (id & 7) * 128, 1024, 2);
}

// ---------------- fused attention: heads-softmax + attn write + PV ----------------
// WG = (b, 16 q-rows), 8 waves. Per 128-k chunk:
//   phase A: wave w owns k-tile kc+16w; swapped QK^T (mfma(K,Q)) -> lane holds all 16
//            head-logits for its (q,k) -> per-lane softmax over h -> f32 direct store
//            to attn output + f16 into LDS.
//   phase B: wave w owns heads {w, w+8}; PV via 16x16x16 MFMA, attn A-frag straight
//            from LDS, V B-frag from pre-transposed Vt (8B contiguous loads).
__global__ __launch_bounds__(512, 2) void attn_fused_k(
    const _Float16* __restrict__ Qh, const _Float16* __restrict__ Kh,
    const _Float16* __restrict__ Vt, float* __restrict__ attnp,
    _Float16* __restrict__ Oh)
{
  const int tid = (int)threadIdx.x;
  const int lane = tid & 63, wv = tid >> 6;
  const int col = lane & 15, g = lane >> 4;
  const int b = (int)blockIdx.y;
  const int q0 = (int)blockIdx.x * 16;

  __shared__ alignas(16) _Float16 plds[16][16][136];  // [h][q][k+pad], 16B-aligned rows

  fx4 oacc[2][4];
#pragma unroll
  for (int i = 0; i < 2; ++i)
#pragma unroll
    for (int j = 0; j < 4; ++j) oacc[i][j] = fx4{0.f, 0.f, 0.f, 0.f};

  const _Float16* Qrow = Qh + (size_t)(b * 2048 + q0 + col) * 1024 + g * 8;
  const _Float16* Krow = Kh + (size_t)(b * 2048 + col) * 1024 + g * 8;

  for (int kc = 0; kc < 2048; kc += 128) {
    const int kt = kc + wv * 16;
    fx4 lg[16];
#pragma unroll
    for (int h = 0; h < 16; ++h) lg[h] = fx4{0.f, 0.f, 0.f, 0.f};
#pragma unroll
    for (int h = 0; h < 16; ++h) {
#pragma unroll
      for (int ks = 0; ks < 2; ++ks) {
        hf8 ka = *(const hf8*)(Krow + (size_t)kt * 1024 + h * 64 + ks * 32);
        hf8 qa = *(const hf8*)(Qrow + h * 64 + ks * 32);
        lg[h] = __builtin_amdgcn_mfma_f32_16x16x32_f16(ka, qa, lg[h], 0, 0, 0);
      }
    }
    // softmax over heads, per lane; element r <-> (q=q0+col, k=kt+4g+r)
    fx4 mx = lg[0];
#pragma unroll
    for (int h = 1; h < 16; ++h)
#pragma unroll
      for (int r = 0; r < 4; ++r) mx[r] = fmaxf(mx[r], lg[h][r]);
    fx4 sm = fx4{0.f, 0.f, 0.f, 0.f};
#pragma unroll
    for (int h = 0; h < 16; ++h)
#pragma unroll
      for (int r = 0; r < 4; ++r) {
        float p = __expf((lg[h][r] - mx[r]) * 0.125f);
        lg[h][r] = p;
        sm[r] += p;
      }
#pragma unroll
    for (int r = 0; r < 4; ++r) sm[r] = 1.f / sm[r];

#pragma unroll
    for (int h = 0; h < 16; ++h) {
      fx4 av;
#pragma unroll
      for (int r = 0; r < 4; ++r) av[r] = lg[h][r] * sm[r];
      *(fx4*)(attnp + (size_t)((b * 16 + h) * 2048 + q0 + col) * 2048 + kt + 4 * g) = av;
      hf4 pk = {(_Float16)av[0], (_Float16)av[1], (_Float16)av[2], (_Float16)av[3]};
      *(hf4*)&plds[h][col][wv * 16 + 4 * g] = pk;
    }
    __syncthreads();

    // PV: wave handles heads wv and wv+8
#pragma unroll
    for (int hh = 0; hh < 2; ++hh) {
      const int h = wv + hh * 8;
      const _Float16* vb0 = Vt + (size_t)(h * 64 + col) * 4096 + b * 2048 + kc + 4 * g;
#pragma unroll
      for (int ks = 0; ks < 8; ++ks) {
        hf4 pa = *(const hf4*)&plds[h][col][ks * 16 + 4 * g];
#pragma unroll
        for (int dt = 0; dt < 4; ++dt) {
          hf4 vb = *(const hf4*)(vb0 + (size_t)dt * 16 * 4096 + ks * 16);
          oacc[hh][dt] = __builtin_amdgcn_mfma_f32_16x16x16f16(pa, vb, oacc[hh][dt], 0, 0, 0);
        }
      }
    }
    __syncthreads();
  }

#pragma unroll
  for (int hh = 0; hh < 2; ++hh) {
    const int h = wv + hh * 8;
#pragma unroll
    for (int dt = 0; dt < 4; ++dt)
#pragma unroll
      for (int r = 0; r < 4; ++r)
        Oh[(size_t)(b * 2048 + q0 + 4 * g + r) * 1024 + h * 64 + dt * 16 + col] =
            (_Float16)oacc[hh][dt][r];
  }
}

// ---------------- launcher ----------------
extern "C" void kernel_launch(void* const* d_in, const int* in_sizes, int n_in,
                              void* d_out, int out_size, void* d_ws, size_t ws_size,
                              hipStream_t stream) {
  (void)in_sizes; (void)n_in; (void)out_size; (void)ws_size;
  const float* x  = (const float*)d_in[0];
  const float* Wq = (const float*)d_in[1];
  const float* bq = (const float*)d_in[2];
  const float* Wk = (const float*)d_in[3];
  const float* bk = (const float*)d_in[4];
  const float* Wv = (const float*)d_in[5];
  const float* bv = (const float*)d_in[6];
  const float* Wo = (const float*)d_in[7];
  const float* bo = (const float*)d_in[8];

  char* ws = (char*)d_ws;                         // layout (MB offsets):
  _Float16* xh  = (_Float16*)(ws + (0ull  << 20)); // 0..8    x fp16 [4096][1024]
  _Float16* Wqh = (_Float16*)(ws + (8ull  << 20)); // 8..10
  _Float16* Wkh = (_Float16*)(ws + (10ull << 20)); // 10..12
  _Float16* Wvh = (_Float16*)(ws + (12ull << 20)); // 12..14
  _Float16* Woh = (_Float16*)(ws + (14ull << 20)); // 14..16
  _Float16* Qh  = (_Float16*)(ws + (16ull << 20)); // 16..24  Q fp16 [4096][1024]
  _Float16* Kh  = (_Float16*)(ws + (24ull << 20)); // 24..32  K fp16
  _Float16* Vt  = (_Float16*)(ws + (32ull << 20)); // 32..40  V^T fp16 [1024][4096]
  _Float16* Oh  = (_Float16*)(ws + (40ull << 20)); // 40..48  attn-out fp16 [4096][1024]

  float* outp  = (float*)d_out;
  float* attnp = outp + 4194304ull;  // attn region [2][16][2048][2048] f32

  cvt_x_k<<<4096, 256, 0, stream>>>(x, xh);
  cvt_w_k<<<dim3(1024, 4), 256, 0, stream>>>(Wq, Wk, Wv, Wo, Wqh);
  qkv_gemm_k<<<768, 256, 0, stream>>>(xh, Wqh, Wkh, Wvh, bq, bk, bv, Qh, Kh, Vt);
  attn_fused_k<<<dim3(128, 2), 512, 0, stream>>>(Qh, Kh, Vt, attnp, Oh);
  out_gemm_k<<<256, 256, 0, stream>>>(Oh, Woh, bo, outp);
}